// Round 3
// baseline (416.760 us; speedup 1.0000x reference)
//
#include <hip/hip_runtime.h>
#include <hip/hip_bf16.h>

#define NN      50000
#define DEG     16
#define FDIM    128
#define KA      273        // 2*128 + 1 + 16
#define KA_PAD  276
#define BSTRIDE 132

__device__ __forceinline__ float fast_tanh(float xv) {
    float ax = fabsf(xv);
    float e2 = __expf(2.0f * ax);
    float r  = 1.0f - 2.0f / (e2 + 1.0f);
    return copysignf(r, xv);
}

__device__ __forceinline__ float wave_reduce_add(float v) {
#pragma unroll
    for (int m = 32; m >= 1; m >>= 1) v += __shfl_xor(v, m, 64);
    return v;
}

// Computes out[32][128] = act(in[32][K] @ W[K][128] + b (+ extra*Wrow)) into LDS.
// Thread map: wave w -> 8 rows [w*8, w*8+8); lane l -> features {l, l+64}.
template<int K, int IN_STRIDE, bool TANH, bool EXTRA>
__device__ __forceinline__ void layer_lds(
    const float* in_lds, float* out_lds,
    const float* __restrict__ W, const float* __restrict__ b,
    const float* extra_lds, const float* __restrict__ Wrow, int tid)
{
    const int l  = tid & 63;
    const int w  = tid >> 6;
    const int f0 = l, f1 = l + 64;
    const int eb = w * 8;
    float acc0[8], acc1[8];
    const float b0 = b[f0], b1 = b[f1];
#pragma unroll
    for (int e = 0; e < 8; ++e) { acc0[e] = b0; acc1[e] = b1; }
    int k = 0;
#pragma unroll 4
    for (; k + 4 <= K; k += 4) {
        float w00 = W[(k + 0) * FDIM + f0];
        float w01 = W[(k + 1) * FDIM + f0];
        float w02 = W[(k + 2) * FDIM + f0];
        float w03 = W[(k + 3) * FDIM + f0];
        float w10 = W[(k + 0) * FDIM + f1];
        float w11 = W[(k + 1) * FDIM + f1];
        float w12 = W[(k + 2) * FDIM + f1];
        float w13 = W[(k + 3) * FDIM + f1];
#pragma unroll
        for (int e = 0; e < 8; ++e) {
            const float4 a = *reinterpret_cast<const float4*>(&in_lds[(eb + e) * IN_STRIDE + k]);
            acc0[e] = fmaf(a.x, w00, acc0[e]);
            acc1[e] = fmaf(a.x, w10, acc1[e]);
            acc0[e] = fmaf(a.y, w01, acc0[e]);
            acc1[e] = fmaf(a.y, w11, acc1[e]);
            acc0[e] = fmaf(a.z, w02, acc0[e]);
            acc1[e] = fmaf(a.z, w12, acc1[e]);
            acc0[e] = fmaf(a.w, w03, acc0[e]);
            acc1[e] = fmaf(a.w, w13, acc1[e]);
        }
    }
    for (; k < K; ++k) {   // tail (K=273 -> one scalar step)
        float wt0 = W[k * FDIM + f0], wt1 = W[k * FDIM + f1];
#pragma unroll
        for (int e = 0; e < 8; ++e) {
            float a = in_lds[(eb + e) * IN_STRIDE + k];
            acc0[e] = fmaf(a, wt0, acc0[e]);
            acc1[e] = fmaf(a, wt1, acc1[e]);
        }
    }
#pragma unroll
    for (int e = 0; e < 8; ++e) {
        if (EXTRA) {
            float ex = extra_lds[eb + e];
            acc0[e] = fmaf(ex, Wrow[f0], acc0[e]);
            acc1[e] = fmaf(ex, Wrow[f1], acc1[e]);
        }
        float v0 = TANH ? fast_tanh(acc0[e]) : acc0[e];
        float v1 = TANH ? fast_tanh(acc1[e]) : acc1[e];
        out_lds[(eb + e) * BSTRIDE + f0] = v0;
        out_lds[(eb + e) * BSTRIDE + f1] = v1;
    }
}

// Final layer: out[r][128] = in[32][128] @ W + b, written straight to global (no act).
template<int IN_STRIDE>
__device__ __forceinline__ void layer_out_global(
    const float* in_lds, float* __restrict__ out_g, int row0, int row_limit,
    const float* __restrict__ W, const float* __restrict__ b, int tid)
{
    const int l  = tid & 63;
    const int w  = tid >> 6;
    const int f0 = l, f1 = l + 64;
    const int eb = w * 8;
    float acc0[8], acc1[8];
    const float b0 = b[f0], b1 = b[f1];
#pragma unroll
    for (int e = 0; e < 8; ++e) { acc0[e] = b0; acc1[e] = b1; }
#pragma unroll 4
    for (int k = 0; k + 4 <= FDIM; k += 4) {
        float w00 = W[(k + 0) * FDIM + f0];
        float w01 = W[(k + 1) * FDIM + f0];
        float w02 = W[(k + 2) * FDIM + f0];
        float w03 = W[(k + 3) * FDIM + f0];
        float w10 = W[(k + 0) * FDIM + f1];
        float w11 = W[(k + 1) * FDIM + f1];
        float w12 = W[(k + 2) * FDIM + f1];
        float w13 = W[(k + 3) * FDIM + f1];
#pragma unroll
        for (int e = 0; e < 8; ++e) {
            const float4 a = *reinterpret_cast<const float4*>(&in_lds[(eb + e) * IN_STRIDE + k]);
            acc0[e] = fmaf(a.x, w00, acc0[e]);
            acc1[e] = fmaf(a.x, w10, acc1[e]);
            acc0[e] = fmaf(a.y, w01, acc0[e]);
            acc1[e] = fmaf(a.y, w11, acc1[e]);
            acc0[e] = fmaf(a.z, w02, acc0[e]);
            acc1[e] = fmaf(a.z, w12, acc1[e]);
            acc0[e] = fmaf(a.w, w03, acc0[e]);
            acc1[e] = fmaf(a.w, w13, acc1[e]);
        }
    }
#pragma unroll
    for (int e = 0; e < 8; ++e) {
        int r = row0 + eb + e;
        if (r < row_limit) {
            out_g[(size_t)r * FDIM + f0] = acc0[e];
            out_g[(size_t)r * FDIM + f1] = acc1[e];
        }
    }
}

// -------- edge kernel: edges [0, NN), 32 per block --------
// LDS: big[] holds attrs (stride KA_PAD) for layer1, then is REUSED as buf2
// (stride BSTRIDE) from layer2 on. Safe: __syncthreads() separates the last
// attrs read (layer1) from the first aliased write (layer2).
// 52.4 KB total -> 3 blocks/CU (was 69 KB -> 2 blocks/CU).
__global__ __launch_bounds__(256) void edge_kernel(
    const float* __restrict__ h, const float* __restrict__ x,
    const float* __restrict__ ea, const int* __restrict__ cols,
    const float* __restrict__ We1, const float* __restrict__ be1,
    const float* __restrict__ We2, const float* __restrict__ be2,
    const float* __restrict__ Wx1, const float* __restrict__ bx1,
    const float* __restrict__ Wx2, const float* __restrict__ bx2,
    float* __restrict__ msum, float* __restrict__ exsum)
{
    __shared__ __align__(16) float big[32 * KA_PAD];   // attrs, then buf2
    __shared__ __align__(16) float buf1[32 * BSTRIDE];
    __shared__ float sdiff[32];

    float* attrs = big;   // stride KA_PAD
    float* buf2  = big;   // stride BSTRIDE (alias, live after layer1)

    const int tid = threadIdx.x;
    const int e0  = blockIdx.x * 32;

    // ---- stage attrs = [h_i(128) | h_j(128) | dr(1) | ea(16)] ----
    {
        const int el = tid >> 3, q = tid & 7;   // 8 threads per edge row
        int ec = e0 + el; if (ec >= NN) ec = NN - 1;
        const int i = ec >> 4;          // rows[e] == e / 16
        const int j = cols[ec];
        const float4* hi4 = reinterpret_cast<const float4*>(h + (size_t)i * FDIM);
        const float4* hj4 = reinterpret_cast<const float4*>(h + (size_t)j * FDIM);
        float4* d0 = reinterpret_cast<float4*>(&attrs[el * KA_PAD + q * 16]);
        float4* d1 = reinterpret_cast<float4*>(&attrs[el * KA_PAD + 128 + q * 16]);
#pragma unroll
        for (int t = 0; t < 4; ++t) d0[t] = hi4[q * 4 + t];
#pragma unroll
        for (int t = 0; t < 4; ++t) d1[t] = hj4[q * 4 + t];
        if (q < 2) {
#pragma unroll
            for (int t = 0; t < 8; ++t)
                attrs[el * KA_PAD + 257 + q * 8 + t] = ea[(size_t)ec * 16 + q * 8 + t];
        }
        if (q == 2) {
            float dx = x[i * 3 + 0] - x[j * 3 + 0];
            float dy = x[i * 3 + 1] - x[j * 3 + 1];
            float dz = x[i * 3 + 2] - x[j * 3 + 2];
            attrs[el * KA_PAD + 256] = dx * dx + dy * dy + dz * dz;
            sdiff[el] = dx + dy + dz;
        }
    }
    __syncthreads();

    // t1 = tanh(attrs @ We1 + be1)
    layer_lds<KA, KA_PAD, true, false>(attrs, buf1, We1, be1, nullptr, nullptr, tid);
    __syncthreads();   // all attrs reads done -> big may be reused as buf2

    // m = tanh(t1 @ We2 + be2)   (writes alias big/buf2)
    layer_lds<FDIM, BSTRIDE, true, false>(buf1, buf2, We2, be2, nullptr, nullptr, tid);
    __syncthreads();

    const int l = tid & 63, w = tid >> 6, eb = w * 8;

    // msum[e] = sum_f m[e][f]
#pragma unroll
    for (int e = 0; e < 8; ++e) {
        float s = buf2[(eb + e) * BSTRIDE + l] + buf2[(eb + e) * BSTRIDE + l + 64];
        s = wave_reduce_add(s);
        if (l == 0) {
            int eg = e0 + eb + e;
            if (eg < NN) msum[eg] = s;
        }
    }

    // t2 = tanh(m @ Wx1 + bx1)
    layer_lds<FDIM, BSTRIDE, true, false>(buf2, buf1, Wx1, bx1, nullptr, nullptr, tid);
    __syncthreads();

    // phi = tanh(t2 . Wx2 + bx2); exsum[e] = phi * (dx+dy+dz)
    {
        const float wx0 = Wx2[l], wx1 = Wx2[l + 64];
        const float bxx = bx2[0];
#pragma unroll
        for (int e = 0; e < 8; ++e) {
            float s = buf1[(eb + e) * BSTRIDE + l] * wx0
                    + buf1[(eb + e) * BSTRIDE + l + 64] * wx1;
            s = wave_reduce_add(s);
            if (l == 0) {
                int eg = e0 + eb + e;
                if (eg < NN) exsum[eg] = fast_tanh(s + bxx) * sdiff[eb + e];
            }
        }
    }
}

// -------- node kernel: nodes [0, NN), 32 per block --------
__global__ __launch_bounds__(256) void node_kernel(
    const float* __restrict__ h, const float* __restrict__ x,
    const float* __restrict__ vel, const int* __restrict__ cols,
    const float* __restrict__ Wh1, const float* __restrict__ bh1,
    const float* __restrict__ Wh2, const float* __restrict__ bh2,
    const float* __restrict__ Wv1, const float* __restrict__ bv1,
    const float* __restrict__ Wv2, const float* __restrict__ bv2,
    const float* __restrict__ msum, const float* __restrict__ exsum,
    float* __restrict__ out_h, float* __restrict__ out_x, float* __restrict__ out_v)
{
    __shared__ __align__(16) float hn[32 * BSTRIDE];
    __shared__ __align__(16) float buf1[32 * BSTRIDE];
    __shared__ float mi[32], media[32], phiv[32];

    const int tid = threadIdx.x;
    const int n0  = blockIdx.x * 32;

    // stage h rows (contiguous nodes)
    {
        const int el = tid >> 3, q = tid & 7;
        int nc = n0 + el; if (nc >= NN) nc = NN - 1;
        const float4* hr = reinterpret_cast<const float4*>(h + (size_t)nc * FDIM);
        float4* d = reinterpret_cast<float4*>(&hn[el * BSTRIDE + q * 16]);
#pragma unroll
        for (int t = 0; t < 4; ++t) d[t] = hr[q * 4 + t];
    }
    // gather m_i and media: node i's edges are [16i, 16i+16)
    {
#pragma unroll
        for (int r = 0; r < 2; ++r) {
            int idx = tid + r * 256;        // 0..511 = 32 nodes x 16
            int nl = idx >> 4, kk = idx & 15;
            int nc = n0 + nl; if (nc >= NN) nc = NN - 1;
            int c = cols[(size_t)nc * DEG + kk];
            float ms = msum[c];
            float ex = exsum[c];
#pragma unroll
            for (int m = 8; m >= 1; m >>= 1) {
                ms += __shfl_xor(ms, m, 64);
                ex += __shfl_xor(ex, m, 64);
            }
            if (kk == 0) { mi[nl] = ms; media[nl] = ex * (1.0f / 16.0f); }
        }
    }
    __syncthreads();

    // tv = tanh(h @ Wv1 + bv1)
    layer_lds<FDIM, BSTRIDE, true, false>(hn, buf1, Wv1, bv1, nullptr, nullptr, tid);
    __syncthreads();

    const int l = tid & 63, w = tid >> 6, eb = w * 8;
    // phi_v = tv . Wv2 + bv2   (no output tanh)
    {
        const float wv0 = Wv2[l], wv1 = Wv2[l + 64];
        const float bvv = bv2[0];
#pragma unroll
        for (int e = 0; e < 8; ++e) {
            float s = buf1[(eb + e) * BSTRIDE + l] * wv0
                    + buf1[(eb + e) * BSTRIDE + l + 64] * wv1;
            s = wave_reduce_add(s);
            if (l == 0) phiv[eb + e] = s + bvv;
        }
    }
    __syncthreads();

    // th = tanh([h, m_i] @ Wh1 + bh1)   (k=129: extra row 128 of Wh1)
    layer_lds<FDIM, BSTRIDE, true, true>(hn, buf1, Wh1, bh1, mi,
                                         Wh1 + (size_t)FDIM * FDIM, tid);
    __syncthreads();

    // h_new = th @ Wh2 + bh2 -> global
    layer_out_global<BSTRIDE>(buf1, out_h, n0, NN, Wh2, bh2, tid);

    // vel_new / x_new
    if (tid < 96) {
        int nl = tid / 3, d = tid % 3;
        int n = n0 + nl;
        if (n < NN) {
            float pv = phiv[nl], md = media[nl];
            float vv = vel[(size_t)n * 3 + d] * pv + md;
            out_v[(size_t)n * 3 + d] = vv;
            out_x[(size_t)n * 3 + d] = x[(size_t)n * 3 + d] + vv;
        }
    }
}

extern "C" void kernel_launch(void* const* d_in, const int* in_sizes, int n_in,
                              void* d_out, int out_size, void* d_ws, size_t ws_size,
                              hipStream_t stream)
{
    (void)in_sizes; (void)n_in; (void)out_size; (void)ws_size;
    const float* h    = (const float*)d_in[0];
    const float* x    = (const float*)d_in[1];
    const float* vel  = (const float*)d_in[2];
    const float* ea   = (const float*)d_in[3];
    const int*   cols = (const int*)d_in[5];
    const float* We1 = (const float*)d_in[6];  const float* be1 = (const float*)d_in[7];
    const float* We2 = (const float*)d_in[8];  const float* be2 = (const float*)d_in[9];
    const float* Wx1 = (const float*)d_in[10]; const float* bx1 = (const float*)d_in[11];
    const float* Wx2 = (const float*)d_in[12]; const float* bx2 = (const float*)d_in[13];
    const float* Wh1 = (const float*)d_in[14]; const float* bh1 = (const float*)d_in[15];
    const float* Wh2 = (const float*)d_in[16]; const float* bh2 = (const float*)d_in[17];
    const float* Wv1 = (const float*)d_in[18]; const float* bv1 = (const float*)d_in[19];
    const float* Wv2 = (const float*)d_in[20]; const float* bv2 = (const float*)d_in[21];

    float* msum  = (float*)d_ws;
    float* exsum = msum + NN;
    float* out_h = (float*)d_out;
    float* out_x = out_h + (size_t)NN * FDIM;
    float* out_v = out_x + (size_t)NN * 3;

    dim3 grid((NN + 31) / 32), block(256);
    edge_kernel<<<grid, block, 0, stream>>>(h, x, ea, cols,
                                            We1, be1, We2, be2, Wx1, bx1, Wx2, bx2,
                                            msum, exsum);
    node_kernel<<<grid, block, 0, stream>>>(h, x, vel, cols,
                                            Wh1, bh1, Wh2, bh2, Wv1, bv1, Wv2, bv2,
                                            msum, exsum, out_h, out_x, out_v);
}

// Round 4
// 212.795 us; speedup vs baseline: 1.9585x; 1.9585x over previous
//
#include <hip/hip_runtime.h>
#include <hip/hip_bf16.h>

#define NN      50000
#define DEG     16
#define FDIM    128
#define ASTR    296     // attrs LDS row stride (bf16): 148 words % 32 = 20 -> 8-bank spread
#define OSTR    136     // activation LDS row stride (bf16): 68 words % 32 = 4 -> 8-bank spread
// ws layout (shorts): We1t[128][288] | We2t,Wx1t,Wv1t,Wh1t,Wh2t each [128][128]
#define OFF_WE1 0
#define OFF_WE2 36864
#define OFF_WX1 53248
#define OFF_WV1 69632
#define OFF_WH1 86016
#define OFF_WH2 102400
#define WS_SHORTS 118784

typedef short v8s  __attribute__((ext_vector_type(8)));
typedef short v4sh __attribute__((ext_vector_type(4)));
typedef short v2sh __attribute__((ext_vector_type(2)));
typedef float v4f  __attribute__((ext_vector_type(4)));

__device__ __forceinline__ float fast_tanh(float xv) {
    float ax = fabsf(xv);
    float e2 = __expf(2.0f * ax);
    float r  = 1.0f - 2.0f / (e2 + 1.0f);
    return copysignf(r, xv);
}

__device__ __forceinline__ short f2bf(float f) {   // RNE float->bf16
    union { float f; unsigned u; } a; a.f = f;
    unsigned r = a.u + 0x7fffu + ((a.u >> 16) & 1u);
    return (short)(unsigned short)(r >> 16);
}
__device__ __forceinline__ float bf2f(short s) {
    union { unsigned u; float f; } a; a.u = ((unsigned)(unsigned short)s) << 16;
    return a.f;
}

__device__ __forceinline__ float wave_reduce_add(float v) {
#pragma unroll
    for (int m = 32; m >= 1; m >>= 1) v += __shfl_xor(v, m, 64);
    return v;
}

// acc[2][2] over M=32 (2 tiles), this wave's 32 cols (2 tiles), K = KSTEPS*32.
// A in LDS bf16 [32][ASTRIDE]; Wt in global bf16 [128][KPAD] (col-major rows).
template<int KSTEPS, int ASTRIDE, int KPAD>
__device__ __forceinline__ void mfma_acc(
    const short* A, const short* __restrict__ Wt, int l, int w, v4f acc[2][2])
{
    const int lm = l & 15, lk = l >> 4;
    const short* a0p = A + lm * ASTRIDE + lk * 8;
    const short* a1p = a0p + 16 * ASTRIDE;
    const short* b0p = Wt + (w * 32 + lm) * KPAD + lk * 8;
    const short* b1p = b0p + 16 * KPAD;
#pragma unroll
    for (int ks = 0; ks < KSTEPS; ++ks) {
        v8s a0 = *(const v8s*)(a0p + ks * 32);
        v8s a1 = *(const v8s*)(a1p + ks * 32);
        v8s b0 = *(const v8s*)(b0p + ks * 32);
        v8s b1 = *(const v8s*)(b1p + ks * 32);
        acc[0][0] = __builtin_amdgcn_mfma_f32_16x16x32_bf16(a0, b0, acc[0][0], 0, 0, 0);
        acc[1][0] = __builtin_amdgcn_mfma_f32_16x16x32_bf16(a1, b0, acc[1][0], 0, 0, 0);
        acc[0][1] = __builtin_amdgcn_mfma_f32_16x16x32_bf16(a0, b1, acc[0][1], 0, 0, 0);
        acc[1][1] = __builtin_amdgcn_mfma_f32_16x16x32_bf16(a1, b1, acc[1][1], 0, 0, 0);
    }
}

__device__ __forceinline__ void acc_zero(v4f acc[2][2]) {
    v4f z = {0.f, 0.f, 0.f, 0.f};
    acc[0][0] = z; acc[0][1] = z; acc[1][0] = z; acc[1][1] = z;
}

// epilogue: +bias, tanh, bf16 -> LDS [32][OSTR]
__device__ __forceinline__ void epi_to_lds(
    v4f acc[2][2], short* O, const float* __restrict__ b, int l, int w)
{
    const int rl = (l >> 4) * 4, cl = l & 15;
#pragma unroll
    for (int nt = 0; nt < 2; ++nt) {
        const int col = w * 32 + nt * 16 + cl;
        const float bias = b[col];
#pragma unroll
        for (int mt = 0; mt < 2; ++mt) {
#pragma unroll
            for (int r = 0; r < 4; ++r) {
                float v = fast_tanh(acc[mt][nt][r] + bias);
                O[(mt * 16 + rl + r) * OSTR + col] = f2bf(v);
            }
        }
    }
}

// -------- weight prep: fp32 [K][128] -> bf16 Wt [128][KPAD] in ws --------
__global__ __launch_bounds__(256) void prep_weights(
    const float* __restrict__ We1, const float* __restrict__ We2,
    const float* __restrict__ Wx1, const float* __restrict__ Wv1,
    const float* __restrict__ Wh1, const float* __restrict__ Wh2,
    short* __restrict__ wbuf)
{
    int idx = blockIdx.x * 256 + threadIdx.x;
    if (idx < 128 * 288) {                       // We1t with zero K-pad 273..287
        int c = idx / 288, k = idx % 288;
        wbuf[OFF_WE1 + idx] = (k < 273) ? f2bf(We1[k * FDIM + c]) : (short)0;
        return;
    }
    idx -= 128 * 288;
    if (idx < 5 * 16384) {
        int layer = idx / 16384, r = idx % 16384;
        int c = r / 128, k = r % 128;
        const float* W = (layer == 0) ? We2 : (layer == 1) ? Wx1 :
                         (layer == 2) ? Wv1 : (layer == 3) ? Wh1 : Wh2;
        wbuf[OFF_WE2 + layer * 16384 + c * 128 + k] = f2bf(W[k * FDIM + c]);
    }
}

// -------- edge kernel: edges [0, NN), 32 per block, 4 waves --------
__global__ __launch_bounds__(256) void edge_kernel(
    const float* __restrict__ h, const float* __restrict__ x,
    const float* __restrict__ ea, const int* __restrict__ cols,
    const short* __restrict__ wbuf,
    const float* __restrict__ be1, const float* __restrict__ be2,
    const float* __restrict__ bx1,
    const float* __restrict__ Wx2, const float* __restrict__ bx2,
    float* __restrict__ msum, float* __restrict__ exsum)
{
    __shared__ __align__(16) short attrs[32 * ASTR];
    __shared__ __align__(16) short buf1[32 * OSTR];
    __shared__ __align__(16) short buf2[32 * OSTR];
    __shared__ float sdiff[32];

    const int tid = threadIdx.x;
    const int e0  = blockIdx.x * 32;
    const int l   = tid & 63, w = tid >> 6, eb = w * 8;

    // ---- stage attrs bf16 = [h_i(128) | h_j(128) | dr | ea(16) | 0-pad->288] ----
    {
        const int el = tid >> 3, q = tid & 7;
        int ec = e0 + el; if (ec >= NN) ec = NN - 1;
        const int i = ec >> 4;              // rows[e] == e/16
        const int j = cols[ec];
        const float4* hi4 = (const float4*)(h + (size_t)i * FDIM);
        const float4* hj4 = (const float4*)(h + (size_t)j * FDIM);
        short* arow = attrs + el * ASTR;
#pragma unroll
        for (int t = 0; t < 4; ++t) {
            float4 v = hi4[q * 4 + t];
            v4sh s = { f2bf(v.x), f2bf(v.y), f2bf(v.z), f2bf(v.w) };
            *(v4sh*)(arow + q * 16 + t * 4) = s;
            float4 u = hj4[q * 4 + t];
            v4sh s2 = { f2bf(u.x), f2bf(u.y), f2bf(u.z), f2bf(u.w) };
            *(v4sh*)(arow + 128 + q * 16 + t * 4) = s2;
        }
        if (q < 2) {
#pragma unroll
            for (int t = 0; t < 8; ++t)
                arow[257 + q * 8 + t] = f2bf(ea[(size_t)ec * 16 + q * 8 + t]);
        }
        if (q == 2) {
            float dx = x[i * 3 + 0] - x[j * 3 + 0];
            float dy = x[i * 3 + 1] - x[j * 3 + 1];
            float dz = x[i * 3 + 2] - x[j * 3 + 2];
            arow[256] = f2bf(dx * dx + dy * dy + dz * dz);
            sdiff[el] = dx + dy + dz;
        }
        if (q == 3) {
#pragma unroll
            for (int t = 0; t < 15; ++t) arow[273 + t] = 0;
        }
    }
    __syncthreads();

    v4f acc[2][2];
    // t1 = tanh(attrs @ We1 + be1)   K=288 (zero-padded)
    acc_zero(acc);
    mfma_acc<9, ASTR, 288>(attrs, wbuf + OFF_WE1, l, w, acc);
    epi_to_lds(acc, buf1, be1, l, w);
    __syncthreads();

    // m = tanh(t1 @ We2 + be2)
    acc_zero(acc);
    mfma_acc<4, OSTR, 128>(buf1, wbuf + OFF_WE2, l, w, acc);
    epi_to_lds(acc, buf2, be2, l, w);
    __syncthreads();

    // msum[e] = sum_f m[e][f]
#pragma unroll
    for (int e = 0; e < 8; ++e) {
        int row = eb + e;
        v2sh p = *(const v2sh*)(buf2 + row * OSTR + 2 * l);
        float s = bf2f(p.x) + bf2f(p.y);
        s = wave_reduce_add(s);
        if (l == 0) {
            int eg = e0 + row;
            if (eg < NN) msum[eg] = s;
        }
    }

    // t2 = tanh(m @ Wx1 + bx1)
    acc_zero(acc);
    mfma_acc<4, OSTR, 128>(buf2, wbuf + OFF_WX1, l, w, acc);
    epi_to_lds(acc, buf1, bx1, l, w);
    __syncthreads();

    // phi = tanh(t2 . Wx2 + bx2); exsum = phi * (dx+dy+dz)
    {
        const float wx0 = Wx2[2 * l], wx1 = Wx2[2 * l + 1];
        const float bxx = bx2[0];
#pragma unroll
        for (int e = 0; e < 8; ++e) {
            int row = eb + e;
            v2sh p = *(const v2sh*)(buf1 + row * OSTR + 2 * l);
            float s = bf2f(p.x) * wx0 + bf2f(p.y) * wx1;
            s = wave_reduce_add(s);
            if (l == 0) {
                int eg = e0 + row;
                if (eg < NN) exsum[eg] = fast_tanh(s + bxx) * sdiff[row];
            }
        }
    }
}

// -------- node kernel: nodes [0, NN), 32 per block, 4 waves --------
__global__ __launch_bounds__(256) void node_kernel(
    const float* __restrict__ h, const float* __restrict__ x,
    const float* __restrict__ vel, const int* __restrict__ cols,
    const short* __restrict__ wbuf,
    const float* __restrict__ bv1, const float* __restrict__ Wv2,
    const float* __restrict__ bv2,
    const float* __restrict__ bh1, const float* __restrict__ Wh1f,
    const float* __restrict__ bh2,
    const float* __restrict__ msum, const float* __restrict__ exsum,
    float* __restrict__ out_h, float* __restrict__ out_x, float* __restrict__ out_v)
{
    __shared__ __align__(16) short hn[32 * OSTR];
    __shared__ __align__(16) short buf1[32 * OSTR];
    __shared__ float mi[32], media[32], phiv[32];

    const int tid = threadIdx.x;
    const int n0  = blockIdx.x * 32;
    const int l   = tid & 63, w = tid >> 6, eb = w * 8;

    // stage h rows -> bf16 LDS
    {
        const int el = tid >> 3, q = tid & 7;
        int nc = n0 + el; if (nc >= NN) nc = NN - 1;
        const float4* hr = (const float4*)(h + (size_t)nc * FDIM);
        short* arow = hn + el * OSTR;
#pragma unroll
        for (int t = 0; t < 4; ++t) {
            float4 v = hr[q * 4 + t];
            v4sh s = { f2bf(v.x), f2bf(v.y), f2bf(v.z), f2bf(v.w) };
            *(v4sh*)(arow + q * 16 + t * 4) = s;
        }
    }
    // gather m_i and media (node i's edges are [16i,16i+16))
    {
#pragma unroll
        for (int r = 0; r < 2; ++r) {
            int idx = tid + r * 256;
            int nl = idx >> 4, kk = idx & 15;
            int nc = n0 + nl; if (nc >= NN) nc = NN - 1;
            int c = cols[(size_t)nc * DEG + kk];
            float ms = msum[c];
            float ex = exsum[c];
#pragma unroll
            for (int m = 8; m >= 1; m >>= 1) {
                ms += __shfl_xor(ms, m, 64);
                ex += __shfl_xor(ex, m, 64);
            }
            if (kk == 0) { mi[nl] = ms; media[nl] = ex * (1.0f / 16.0f); }
        }
    }
    __syncthreads();

    v4f acc[2][2];
    // tv = tanh(h @ Wv1 + bv1)
    acc_zero(acc);
    mfma_acc<4, OSTR, 128>(hn, wbuf + OFF_WV1, l, w, acc);
    epi_to_lds(acc, buf1, bv1, l, w);
    __syncthreads();

    // phi_v = tv . Wv2 + bv2
    {
        const float wv0 = Wv2[2 * l], wv1 = Wv2[2 * l + 1];
        const float bvv = bv2[0];
#pragma unroll
        for (int e = 0; e < 8; ++e) {
            int row = eb + e;
            v2sh p = *(const v2sh*)(buf1 + row * OSTR + 2 * l);
            float s = bf2f(p.x) * wv0 + bf2f(p.y) * wv1;
            s = wave_reduce_add(s);
            if (l == 0) phiv[row] = s + bvv;
        }
    }
    __syncthreads();

    // th = tanh([h|m_i] @ Wh1 + bh1): MFMA over K=128 + mi*Wh1[128][:] in epilogue
    acc_zero(acc);
    mfma_acc<4, OSTR, 128>(hn, wbuf + OFF_WH1, l, w, acc);
    {
        const int rl = (l >> 4) * 4, cl = l & 15;
        const float* w128 = Wh1f + (size_t)FDIM * FDIM;
#pragma unroll
        for (int nt = 0; nt < 2; ++nt) {
            const int col = w * 32 + nt * 16 + cl;
            const float bias = bh1[col], wr = w128[col];
#pragma unroll
            for (int mt = 0; mt < 2; ++mt) {
#pragma unroll
                for (int r = 0; r < 4; ++r) {
                    int row = mt * 16 + rl + r;
                    float v = fast_tanh(acc[mt][nt][r] + bias + mi[row] * wr);
                    buf1[row * OSTR + col] = f2bf(v);
                }
            }
        }
    }
    __syncthreads();

    // h_new = th @ Wh2 + bh2 -> global fp32
    acc_zero(acc);
    mfma_acc<4, OSTR, 128>(buf1, wbuf + OFF_WH2, l, w, acc);
    {
        const int rl = (l >> 4) * 4, cl = l & 15;
#pragma unroll
        for (int nt = 0; nt < 2; ++nt) {
            const int col = w * 32 + nt * 16 + cl;
            const float bias = bh2[col];
#pragma unroll
            for (int mt = 0; mt < 2; ++mt) {
#pragma unroll
                for (int r = 0; r < 4; ++r) {
                    int rg = n0 + mt * 16 + rl + r;
                    if (rg < NN) out_h[(size_t)rg * FDIM + col] = acc[mt][nt][r] + bias;
                }
            }
        }
    }

    // vel_new / x_new
    if (tid < 96) {
        int nl = tid / 3, d = tid % 3;
        int n = n0 + nl;
        if (n < NN) {
            float vv = vel[(size_t)n * 3 + d] * phiv[nl] + media[nl];
            out_v[(size_t)n * 3 + d] = vv;
            out_x[(size_t)n * 3 + d] = x[(size_t)n * 3 + d] + vv;
        }
    }
}

extern "C" void kernel_launch(void* const* d_in, const int* in_sizes, int n_in,
                              void* d_out, int out_size, void* d_ws, size_t ws_size,
                              hipStream_t stream)
{
    (void)in_sizes; (void)n_in; (void)out_size; (void)ws_size;
    const float* h    = (const float*)d_in[0];
    const float* x    = (const float*)d_in[1];
    const float* vel  = (const float*)d_in[2];
    const float* ea   = (const float*)d_in[3];
    const int*   cols = (const int*)d_in[5];
    const float* We1 = (const float*)d_in[6];  const float* be1 = (const float*)d_in[7];
    const float* We2 = (const float*)d_in[8];  const float* be2 = (const float*)d_in[9];
    const float* Wx1 = (const float*)d_in[10]; const float* bx1 = (const float*)d_in[11];
    const float* Wx2 = (const float*)d_in[12]; const float* bx2 = (const float*)d_in[13];
    const float* Wh1 = (const float*)d_in[14]; const float* bh1 = (const float*)d_in[15];
    const float* Wh2 = (const float*)d_in[16]; const float* bh2 = (const float*)d_in[17];
    const float* Wv1 = (const float*)d_in[18]; const float* bv1 = (const float*)d_in[19];
    const float* Wv2 = (const float*)d_in[20]; const float* bv2 = (const float*)d_in[21];

    short* wbuf  = (short*)d_ws;
    float* msum  = (float*)((char*)d_ws + WS_SHORTS * sizeof(short));
    float* exsum = msum + NN;
    float* out_h = (float*)d_out;
    float* out_x = out_h + (size_t)NN * FDIM;
    float* out_v = out_x + (size_t)NN * 3;

    dim3 block(256);
    prep_weights<<<dim3((WS_SHORTS + 255) / 256), block, 0, stream>>>(
        We1, We2, Wx1, Wv1, Wh1, Wh2, wbuf);
    dim3 grid((NN + 31) / 32);
    edge_kernel<<<grid, block, 0, stream>>>(h, x, ea, cols, wbuf,
                                            be1, be2, bx1, Wx2, bx2, msum, exsum);
    node_kernel<<<grid, block, 0, stream>>>(h, x, vel, cols, wbuf,
                                            bv1, Wv2, bv2, bh1, Wh1, bh2,
                                            msum, exsum, out_h, out_x, out_v);
}